// Round 5
// baseline (251.118 us; speedup 1.0000x reference)
//
#include <hip/hip_runtime.h>

typedef __bf16 bf16x8 __attribute__((ext_vector_type(8)));
typedef float f32x4 __attribute__((ext_vector_type(4)));
typedef float f32x16 __attribute__((ext_vector_type(16)));
typedef unsigned short u16x4 __attribute__((ext_vector_type(4)));
typedef unsigned int u32x4 __attribute__((ext_vector_type(4)));

#define L2E 1.44269504088896340736f

__device__ __forceinline__ f32x4 mfma16(bf16x8 a, bf16x8 b, f32x4 c) {
  return __builtin_amdgcn_mfma_f32_16x16x32_bf16(a, b, c, 0, 0, 0);
}
__device__ __forceinline__ f32x16 mfma32(bf16x8 a, bf16x8 b, f32x16 c) {
  return __builtin_amdgcn_mfma_f32_32x32x16_bf16(a, b, c, 0, 0, 0);
}

// global -> LDS direct copy, 16B per lane. LDS dest must be wave-uniform;
// lane l lands at dest + l*16 bytes.
__device__ __forceinline__ void async16(const __bf16* g, __bf16* l) {
  __builtin_amdgcn_global_load_lds(
      (const __attribute__((address_space(1))) void*)g,
      (__attribute__((address_space(3))) void*)l, 16, 0, 0);
}

// pack two f32 -> one u32 of 2 bf16 (lo=x, hi=y)
__device__ __forceinline__ unsigned pk(float x, float y) {
  unsigned short lo = __builtin_bit_cast(unsigned short, (__bf16)x);
  unsigned short hi = __builtin_bit_cast(unsigned short, (__bf16)y);
  return ((unsigned)hi << 16) | (unsigned)lo;
}

// exchange halves: a' = [a_lo | b_lo], b' = [a_hi | b_hi]
__device__ __forceinline__ void swap32(unsigned& a, unsigned& b, bool hi) {
  unsigned ax = (unsigned)__shfl_xor((int)a, 32);
  unsigned bx = (unsigned)__shfl_xor((int)b, 32);
  unsigned na = hi ? bx : a;
  unsigned nb = hi ? b : ax;
  a = na; b = nb;
}

// ---------------- fp32 -> bf16 conversion (vectorized) ----------------
__global__ __launch_bounds__(256) void cvt_bf16(const float* __restrict__ s,
                                                __bf16* __restrict__ d) {
  long i = (long)(blockIdx.x * 256 + threadIdx.x) * 4;
  f32x4 v = *(const f32x4*)(s + i);
  u16x4 o;
#pragma unroll
  for (int j = 0; j < 4; j++) o[j] = __builtin_bit_cast(unsigned short, (__bf16)v[j]);
  *(u16x4*)((unsigned short*)d + i) = o;
}

// ---------------- bf16 GEMM: C[M,N] = A[M,K] @ Bt[N,K]^T ----------------
// 128x128 tile, BK=32, 4 waves, 16x16x32 MFMA, global_load_lds staging.
// Strided views supported (lda/ldb/ldc) so fused buffers can be sliced.
// LDS layout swizzled: tile[row][c] stored at LDS[row*32 + (c ^ 8*(row&3))].
template <int OUTF32>
__global__ __launch_bounds__(256, 2) void gemm_bt(
    const __bf16* __restrict__ A, const __bf16* __restrict__ Bt,
    void* __restrict__ Cout, const float* __restrict__ bias,
    int lda, int ldb, int ldc, int N, int K, float scale) {
  __shared__ __align__(16) __bf16 As[4096];
  __shared__ __align__(16) __bf16 Bs[4096];
  const int tid = threadIdx.x;
  const int wid = tid >> 6, lane = tid & 63;
  const int lrow = lane & 15, lkhi = lane >> 4;
  const int row0 = blockIdx.x * 128, col0 = blockIdx.y * 128;
  const int wr = (wid >> 1) * 64, wc = (wid & 1) * 64;

  const int trow = tid >> 2;                       // tile row within issue
  const int scol = 8 * ((tid & 3) ^ (trow & 3));   // pre-swizzled source col
  const __bf16* pA0 = A + (size_t)(row0 + trow) * lda + scol;
  const __bf16* pA1 = pA0 + (size_t)64 * lda;
  const __bf16* pB0 = Bt + (size_t)(col0 + trow) * ldb + scol;
  const __bf16* pB1 = pB0 + (size_t)64 * ldb;
  __bf16* lA0 = As + wid * 512;
  __bf16* lA1 = As + 2048 + wid * 512;
  __bf16* lB0 = Bs + wid * 512;
  __bf16* lB1 = Bs + 2048 + wid * 512;

  int aoff[4], boff[4];
#pragma unroll
  for (int i = 0; i < 4; i++) {
    int rr = wr + i * 16 + lrow;
    aoff[i] = rr * 32 + 8 * (lkhi ^ (rr & 3));
    rr = wc + i * 16 + lrow;
    boff[i] = rr * 32 + 8 * (lkhi ^ (rr & 3));
  }

  f32x4 acc[4][4] = {};
  for (int k0 = 0; k0 < K; k0 += 32) {
    __syncthreads();
    async16(pA0, lA0);
    async16(pA1, lA1);
    async16(pB0, lB0);
    async16(pB1, lB1);
    pA0 += 32; pA1 += 32; pB0 += 32; pB1 += 32;
    __syncthreads();
    bf16x8 af[4], bv[4];
#pragma unroll
    for (int mi = 0; mi < 4; mi++) af[mi] = *(const bf16x8*)(As + aoff[mi]);
#pragma unroll
    for (int ni = 0; ni < 4; ni++) bv[ni] = *(const bf16x8*)(Bs + boff[ni]);
#pragma unroll
    for (int mi = 0; mi < 4; mi++)
#pragma unroll
      for (int ni = 0; ni < 4; ni++)
        acc[mi][ni] = mfma16(af[mi], bv[ni], acc[mi][ni]);
  }

  const int orow = row0 + wr + lkhi * 4;
  const int ocol = col0 + wc + lrow;
#pragma unroll
  for (int mi = 0; mi < 4; mi++)
#pragma unroll
    for (int ni = 0; ni < 4; ni++)
#pragma unroll
      for (int r = 0; r < 4; r++) {
        size_t idx = (size_t)(orow + mi * 16 + r) * ldc + (ocol + ni * 16);
        float v = acc[mi][ni][r] * scale;
        if (OUTF32)
          ((float*)Cout)[idx] = v + bias[ocol + ni * 16];
        else
          ((__bf16*)Cout)[idx] = (__bf16)v;
      }
}

// ---------------- causal flash attention (swapped QK^T, in-reg softmax) --
// Qf,Kf: [B*T, H*DH] bf16 (Q pre-scaled by L2E/sqrt(DH)); Vt: [H*DH,B*T].
// Grid: 512 = B(2)*H(16)*qt(16); ALL blocks co-resident at 2 blocks/CU
// (64KB LDS, <=256 VGPR). Rank mapping pairs complementary q-tiles on the
// same CU (round-robin c, c+256): r<256 -> qt=15-(r>>5), r>=256 -> qt=(r-256)>>5
// => per-CU work uniform (34 tiles) AND two independent blocks overlap stalls.
// S^T = mfma32(K, Q): lane holds 32 P-values for ONE q-row -> softmax fully
// in-register; P repacks to PV A-operand (16 packs + 8 half-swaps).
// K,V double-buffered in LDS, ONE barrier per tile.
__global__ __launch_bounds__(256, 2) void mla_attn(
    const __bf16* __restrict__ Qf, const __bf16* __restrict__ Kf,
    const __bf16* __restrict__ Vt, __bf16* __restrict__ ctx) {
  __shared__ __align__(16) __bf16 Ks[2][64 * 128];  // [key][dh], swz (row&15)
  __shared__ __align__(16) __bf16 Vs[2][128 * 64];  // [dh][key], swz (row&7)

  const int r_ = (int)blockIdx.x;
  const int qt = (r_ < 256) ? (15 - (r_ >> 5)) : ((r_ - 256) >> 5);
  const int bh = r_ & 31;            // XCD class r%8 == bh%8: all 16 q-tiles
  const int h = bh >> 1, b = bh & 1; // of one (b,h) share an XCD L2
  const int tid = threadIdx.x, wid = tid >> 6, lane = tid & 63;
  const int l31 = lane & 31;
  const bool hh = (lane & 32) != 0;  // half index

  const __bf16* Kbh = Kf + (size_t)b * 2048 * 2048 + h * 128;
  const __bf16* Vbh = Vt + (size_t)h * 128 * 4096 + b * 2048;

  auto stage = [&](int k0, int buf) {
#pragma unroll
    for (int i = 0; i < 4; i++) {
      int e = i * 2048 + tid * 8;
      int krow = e >> 7;
      int kcol = (e & 127) ^ (8 * (krow & 15));
      async16(Kbh + (size_t)(k0 + krow) * 2048 + kcol,
              &Ks[buf][i * 2048 + wid * 512]);
    }
#pragma unroll
    for (int i = 0; i < 4; i++) {
      int e = i * 2048 + tid * 8;
      int vrow = e >> 6;
      int vcol = (e & 63) ^ (8 * (vrow & 7));
      async16(Vbh + (size_t)vrow * 4096 + k0 + vcol,
              &Vs[buf][i * 2048 + wid * 512]);
    }
  };

  const int q0 = qt * 128;
  const int nkv = 2 * qt + 2;         // 64-key tiles
  const int q = q0 + wid * 32 + l31;  // this lane's q-row

  // Q fragments (B-operand layout: col=q=lane&31, k-rows (lane>>5)*8+j)
  bf16x8 qb[8];
  const __bf16* qrow =
      Qf + (size_t)(b * 2048 + q) * 2048 + h * 128 + (hh ? 8 : 0);
#pragma unroll
  for (int ds = 0; ds < 8; ds++) qb[ds] = *(const bf16x8*)(qrow + ds * 16);

  f32x16 o[4] = {};
  float mrow = -1e30f, lsum = 0.f;

  int cur = 0;
  stage(0, 0);

  for (int kb = 0; kb < nkv; kb++) {
    const int k0 = kb * 64;
    __syncthreads();  // buf[cur] staged; buf[cur^1] free
    if (kb + 1 < nkv) stage(k0 + 64, cur ^ 1);

    // S^T = K Q^T : sacc[kt][r] = S[key = k0+kt*32+(r&3)+8*(r>>2)+4*hh][q]
    f32x16 sacc[2] = {};
    __builtin_amdgcn_s_setprio(1);
#pragma unroll
    for (int ds = 0; ds < 8; ds++) {
#pragma unroll
      for (int kt = 0; kt < 2; kt++) {
        int row = kt * 32 + l31;
        int col = (ds * 16 + (hh ? 8 : 0)) ^ (8 * (row & 15));
        bf16x8 kf = *(const bf16x8*)(&Ks[cur][row * 128 + col]);
        sacc[kt] = mfma32(kf, qb[ds], sacc[kt]);
      }
    }
    __builtin_amdgcn_s_setprio(0);

    // causal mask (last two tiles only)
    if (kb >= 2 * qt) {
#pragma unroll
      for (int kt = 0; kt < 2; kt++)
#pragma unroll
        for (int r = 0; r < 16; r++) {
          int key = k0 + kt * 32 + (r & 3) + 8 * (r >> 2) + (hh ? 4 : 0);
          if (key > q) sacc[kt][r] = -1e30f;
        }
    }

    // in-register online softmax (s already in log2 units); pairwise max tree
    float t[16];
#pragma unroll
    for (int r = 0; r < 16; r++) t[r] = fmaxf(sacc[0][r], sacc[1][r]);
#pragma unroll
    for (int s = 8; s; s >>= 1)
#pragma unroll
      for (int r = 0; r < s; r++) t[r] = fmaxf(t[r], t[r + s]);
    float pm = fmaxf(t[0], __shfl_xor(t[0], 32));

    if (__any(pm > mrow + 8.f)) {  // deferred rescale (THR=8 log2)
      float mn = fmaxf(mrow, pm);
      float sf = __builtin_amdgcn_exp2f(mrow - mn);
      mrow = mn;
      lsum *= sf;
#pragma unroll
      for (int r = 0; r < 16; r++) {
        int ql = (r & 3) + 8 * (r >> 2) + (hh ? 4 : 0);
        float sr = __shfl(sf, ql);
#pragma unroll
        for (int dt = 0; dt < 4; dt++) o[dt][r] *= sr;
      }
    }
    float ps0 = 0.f, ps1 = 0.f, ps2 = 0.f, ps3 = 0.f;  // striped partial sums
#pragma unroll
    for (int kt = 0; kt < 2; kt++)
#pragma unroll
      for (int r = 0; r < 16; r += 4) {
        float a0 = __builtin_amdgcn_exp2f(sacc[kt][r + 0] - mrow);
        float a1 = __builtin_amdgcn_exp2f(sacc[kt][r + 1] - mrow);
        float a2 = __builtin_amdgcn_exp2f(sacc[kt][r + 2] - mrow);
        float a3 = __builtin_amdgcn_exp2f(sacc[kt][r + 3] - mrow);
        sacc[kt][r + 0] = a0; sacc[kt][r + 1] = a1;
        sacc[kt][r + 2] = a2; sacc[kt][r + 3] = a3;
        ps0 += a0; ps1 += a1; ps2 += a2; ps3 += a3;
      }
    float ps = (ps0 + ps1) + (ps2 + ps3);
    ps += __shfl_xor(ps, 32);
    lsum += ps;

    // O += P V : repack P (lane-local) into A-operand fragments
    __builtin_amdgcn_s_setprio(1);
#pragma unroll
    for (int s = 0; s < 4; s++) {
      const int kt = s >> 1, r8 = (s & 1) * 8;
      unsigned w0 = pk(sacc[kt][r8 + 0], sacc[kt][r8 + 1]);
      unsigned w2 = pk(sacc[kt][r8 + 4], sacc[kt][r8 + 5]);
      unsigned w1 = pk(sacc[kt][r8 + 2], sacc[kt][r8 + 3]);
      unsigned w3 = pk(sacc[kt][r8 + 6], sacc[kt][r8 + 7]);
      swap32(w0, w2, hh);  // -> keys 16s+{0,1}|{8,9} , {4,5}|{12,13}
      swap32(w1, w3, hh);
      u32x4 wv;
      wv.x = w0; wv.y = w1; wv.z = w2; wv.w = w3;
      bf16x8 pa = __builtin_bit_cast(bf16x8, wv);
#pragma unroll
      for (int dt = 0; dt < 4; dt++) {
        int vrow = dt * 32 + l31;
        int vcol = (s * 16 + (hh ? 8 : 0)) ^ (8 * (vrow & 7));
        bf16x8 vf = *(const bf16x8*)(&Vs[cur][vrow * 64 + vcol]);
        o[dt] = mfma32(pa, vf, o[dt]);
      }
    }
    __builtin_amdgcn_s_setprio(0);
    cur ^= 1;
  }

  // epilogue: normalize, gather per-row inv, write ctx
  float inv = 1.f / lsum;
#pragma unroll
  for (int r = 0; r < 16; r++) {
    int ql = (r & 3) + 8 * (r >> 2) + (hh ? 4 : 0);
    float ir = __shfl(inv, ql);
    size_t rowi = (size_t)(b * 2048 + q0 + wid * 32 + ql) * 2048 + h * 128;
#pragma unroll
    for (int dt = 0; dt < 4; dt++)
      ctx[rowi + dt * 32 + l31] = (__bf16)(o[dt][r] * ir);
  }
}

// ---------------- launch ----------------
extern "C" void kernel_launch(void* const* d_in, const int* in_sizes, int n_in,
                              void* d_out, int out_size, void* d_ws, size_t ws_size,
                              hipStream_t stream) {
  (void)in_sizes; (void)n_in; (void)out_size; (void)ws_size;
  const float* x    = (const float*)d_in[0];
  const float* wqd  = (const float*)d_in[1];
  const float* wkvd = (const float*)d_in[2];
  const float* wqup = (const float*)d_in[3];
  const float* wkup = (const float*)d_in[4];
  const float* wvup = (const float*)d_in[5];
  const float* wo   = (const float*)d_in[6];
  const float* bo   = (const float*)d_in[7];

  char* ws = (char*)d_ws;
  const size_t MB = 1024 * 1024;
  __bf16* x_bf     = (__bf16*)(ws + 0);        // 16MB; reused as ctx
  __bf16* q_full   = (__bf16*)(ws + 16 * MB);  // 16MB
  __bf16* k_full   = (__bf16*)(ws + 32 * MB);  // 16MB
  __bf16* vt       = (__bf16*)(ws + 48 * MB);  // 16MB
  __bf16* qkv_lat  = (__bf16*)(ws + 64 * MB);  // 12MB [4096,1536]; reused wo_bf
  __bf16* wqkvd_bf = (__bf16*)(ws + 76 * MB);  // 6MB  [1536,2048] fused
  __bf16* wqup_bf  = (__bf16*)(ws + 82 * MB);  // 4MB
  __bf16* wkup_bf  = (__bf16*)(ws + 86 * MB);  // 2MB
  __bf16* wvup_bf  = (__bf16*)(ws + 88 * MB);  // 2MB -> total 90MB
  __bf16* ctx   = x_bf;      // x_bf dead after fused down-proj
  __bf16* wo_bf = qkv_lat;   // qkv_lat dead after V^T GEMM

  auto cvt = [&](const float* s, __bf16* d, int n) {
    cvt_bf16<<<n / 1024, 256, 0, stream>>>(s, d);
  };
  cvt(x, x_bf, 4096 * 2048);
  cvt(wqd, wqkvd_bf, 1024 * 2048);                  // rows 0..1023
  cvt(wkvd, wqkvd_bf + 1024 * 2048, 512 * 2048);    // rows 1024..1535
  cvt(wqup, wqup_bf, 2048 * 1024);
  cvt(wkup, wkup_bf, 2048 * 512);
  cvt(wvup, wvup_bf, 2048 * 512);

  dim3 blk(256);
  // [Q_lat | C_kv] = x @ [Wq_down; Wkv_down]^T   (fused, N=1536)
  gemm_bt<0><<<dim3(32, 12), blk, 0, stream>>>(x_bf, wqkvd_bf, qkv_lat, nullptr,
                                               2048, 2048, 1536, 1536, 2048, 1.0f);
  // Q = Q_lat @ Wq_up^T, pre-scaled by L2E/sqrt(128) (softmax uses exp2)
  gemm_bt<0><<<dim3(32, 16), blk, 0, stream>>>(qkv_lat, wqup_bf, q_full, nullptr,
                                               1536, 1024, 2048, 2048, 1024,
                                               0.12752039360437355f);
  // K = C_kv @ Wk_up^T
  gemm_bt<0><<<dim3(32, 16), blk, 0, stream>>>(qkv_lat + 1024, wkup_bf, k_full,
                                               nullptr, 1536, 512, 2048, 2048,
                                               512, 1.0f);
  // V^T = Wv_up @ C_kv^T  (same kernel, operand roles swapped)
  gemm_bt<0><<<dim3(16, 32), blk, 0, stream>>>(wvup_bf, qkv_lat + 1024, vt,
                                               nullptr, 512, 1536, 4096, 4096,
                                               512, 1.0f);
  cvt(wo, wo_bf, 2048 * 2048);  // qkv_lat region is free after V^T GEMM
  // ctx = causal_attention(Q, K, V)
  mla_attn<<<512, blk, 0, stream>>>(q_full, k_full, vt, ctx);
  // out = ctx @ Wo^T + bo  (fp32)
  gemm_bt<1><<<dim3(32, 16), blk, 0, stream>>>(ctx, wo_bf, (float*)d_out, bo,
                                               2048, 2048, 2048, 2048, 2048, 1.0f);
}

// Round 8
// 241.010 us; speedup vs baseline: 1.0419x; 1.0419x over previous
//
#include <hip/hip_runtime.h>

typedef __bf16 bf16x8 __attribute__((ext_vector_type(8)));
typedef float f32x4 __attribute__((ext_vector_type(4)));
typedef float f32x16 __attribute__((ext_vector_type(16)));
typedef unsigned short u16x4 __attribute__((ext_vector_type(4)));
typedef unsigned int u32x4 __attribute__((ext_vector_type(4)));

#define L2E 1.44269504088896340736f

__device__ __forceinline__ f32x4 mfma16(bf16x8 a, bf16x8 b, f32x4 c) {
  return __builtin_amdgcn_mfma_f32_16x16x32_bf16(a, b, c, 0, 0, 0);
}
__device__ __forceinline__ f32x16 mfma32(bf16x8 a, bf16x8 b, f32x16 c) {
  return __builtin_amdgcn_mfma_f32_32x32x16_bf16(a, b, c, 0, 0, 0);
}

// global -> LDS direct copy, 16B per lane. LDS dest must be wave-uniform;
// lane l lands at dest + l*16 bytes.
__device__ __forceinline__ void async16(const __bf16* g, __bf16* l) {
  __builtin_amdgcn_global_load_lds(
      (const __attribute__((address_space(1))) void*)g,
      (__attribute__((address_space(3))) void*)l, 16, 0, 0);
}

// pack two f32 -> one u32 of 2 bf16 (lo=x, hi=y)
__device__ __forceinline__ unsigned pk(float x, float y) {
  unsigned short lo = __builtin_bit_cast(unsigned short, (__bf16)x);
  unsigned short hi = __builtin_bit_cast(unsigned short, (__bf16)y);
  return ((unsigned)hi << 16) | (unsigned)lo;
}

// ---------------- fp32 -> bf16 conversion (vectorized) ----------------
__global__ __launch_bounds__(256) void cvt_bf16(const float* __restrict__ s,
                                                __bf16* __restrict__ d) {
  long i = (long)(blockIdx.x * 256 + threadIdx.x) * 4;
  f32x4 v = *(const f32x4*)(s + i);
  u16x4 o;
#pragma unroll
  for (int j = 0; j < 4; j++) o[j] = __builtin_bit_cast(unsigned short, (__bf16)v[j]);
  *(u16x4*)((unsigned short*)d + i) = o;
}

// fused conversion of the five projection weights (one launch).
// regions (blocks of 1024 elems): [0,2048) wqd, [2048,3072) wkvd,
// [3072,5120) wqup, [5120,6144) wkup, [6144,7168) wvup.
__global__ __launch_bounds__(256) void cvt_w(
    const float* __restrict__ wqd, const float* __restrict__ wkvd,
    const float* __restrict__ wqup, const float* __restrict__ wkup,
    const float* __restrict__ wvup, __bf16* __restrict__ dqkv,
    __bf16* __restrict__ dqu, __bf16* __restrict__ dku,
    __bf16* __restrict__ dvu) {
  int bx = blockIdx.x;
  const float* s;
  __bf16* d;
  int off;
  if (bx < 2048)      { s = wqd;  d = dqkv;                off = bx; }
  else if (bx < 3072) { s = wkvd; d = dqkv + 1024 * 2048;  off = bx - 2048; }
  else if (bx < 5120) { s = wqup; d = dqu;                 off = bx - 3072; }
  else if (bx < 6144) { s = wkup; d = dku;                 off = bx - 5120; }
  else                { s = wvup; d = dvu;                 off = bx - 6144; }
  long i = (long)off * 1024 + threadIdx.x * 4;
  f32x4 v = *(const f32x4*)(s + i);
  u16x4 o;
#pragma unroll
  for (int j = 0; j < 4; j++) o[j] = __builtin_bit_cast(unsigned short, (__bf16)v[j]);
  *(u16x4*)((unsigned short*)d + i) = o;
}

// ---------------- bf16 GEMM: C[M,N] = A[M,K] @ Bt[N,K]^T ----------------
// 128x128 tile, BK=32, 4 waves, 16x16x32 MFMA, global_load_lds staging.
// Strided views supported (lda/ldb/ldc). PERMN=1 stores output column c at
// (c&~15)|bitswap23(c&15) -- pre-permutes V^T's key axis so the attention
// PV A-fragment needs NO cross-lane exchange (contraction-index relabeling).
// LDS layout swizzled: tile[row][c] stored at LDS[row*32 + (c ^ 8*(row&3))].
template <int OUTF32, int PERMN = 0>
__global__ __launch_bounds__(256, 3) void gemm_bt(
    const __bf16* __restrict__ A, const __bf16* __restrict__ Bt,
    void* __restrict__ Cout, const float* __restrict__ bias,
    int lda, int ldb, int ldc, int N, int K, float scale) {
  __shared__ __align__(16) __bf16 As[4096];
  __shared__ __align__(16) __bf16 Bs[4096];
  const int tid = threadIdx.x;
  const int wid = tid >> 6, lane = tid & 63;
  const int lrow = lane & 15, lkhi = lane >> 4;
  const int row0 = blockIdx.x * 128, col0 = blockIdx.y * 128;
  const int wr = (wid >> 1) * 64, wc = (wid & 1) * 64;

  const int trow = tid >> 2;                       // tile row within issue
  const int scol = 8 * ((tid & 3) ^ (trow & 3));   // pre-swizzled source col
  const __bf16* pA0 = A + (size_t)(row0 + trow) * lda + scol;
  const __bf16* pA1 = pA0 + (size_t)64 * lda;
  const __bf16* pB0 = Bt + (size_t)(col0 + trow) * ldb + scol;
  const __bf16* pB1 = pB0 + (size_t)64 * ldb;
  __bf16* lA0 = As + wid * 512;
  __bf16* lA1 = As + 2048 + wid * 512;
  __bf16* lB0 = Bs + wid * 512;
  __bf16* lB1 = Bs + 2048 + wid * 512;

  int aoff[4], boff[4];
#pragma unroll
  for (int i = 0; i < 4; i++) {
    int rr = wr + i * 16 + lrow;
    aoff[i] = rr * 32 + 8 * (lkhi ^ (rr & 3));
    rr = wc + i * 16 + lrow;
    boff[i] = rr * 32 + 8 * (lkhi ^ (rr & 3));
  }

  f32x4 acc[4][4] = {};
  for (int k0 = 0; k0 < K; k0 += 32) {
    __syncthreads();
    async16(pA0, lA0);
    async16(pA1, lA1);
    async16(pB0, lB0);
    async16(pB1, lB1);
    pA0 += 32; pA1 += 32; pB0 += 32; pB1 += 32;
    __syncthreads();
    bf16x8 af[4], bv[4];
#pragma unroll
    for (int mi = 0; mi < 4; mi++) af[mi] = *(const bf16x8*)(As + aoff[mi]);
#pragma unroll
    for (int ni = 0; ni < 4; ni++) bv[ni] = *(const bf16x8*)(Bs + boff[ni]);
#pragma unroll
    for (int mi = 0; mi < 4; mi++)
#pragma unroll
      for (int ni = 0; ni < 4; ni++)
        acc[mi][ni] = mfma16(af[mi], bv[ni], acc[mi][ni]);
  }

  const int orow = row0 + wr + lkhi * 4;
  // PERMN: bijective bit2<->bit3 swap of (col & 15); involution, 16-aligned.
  const int prow = PERMN ? ((lrow & 3) | ((lrow & 4) << 1) | ((lrow & 8) >> 1))
                         : lrow;
  const int ocol = col0 + wc + prow;
#pragma unroll
  for (int mi = 0; mi < 4; mi++)
#pragma unroll
    for (int ni = 0; ni < 4; ni++)
#pragma unroll
      for (int r = 0; r < 4; r++) {
        size_t idx = (size_t)(orow + mi * 16 + r) * ldc + (ocol + ni * 16);
        float v = acc[mi][ni][r] * scale;
        if (OUTF32)
          ((float*)Cout)[idx] = v + bias[ocol + ni * 16];
        else
          ((__bf16*)Cout)[idx] = (__bf16)v;
      }
}

// ---------------- causal flash attention (swapped QK^T, in-reg softmax) --
// Qf,Kf: [B*T, H*DH] bf16 (Q pre-scaled by L2E/sqrt(DH)); Vt: [H*DH,B*T]
// with key axis pre-permuted by bitswap23 (see gemm_bt PERMN).
// Grid: 512 = B(2)*H(16)*qt(16), 2 blocks/CU. Rank mapping pairs
// complementary q-tiles on the same CU: r<256 -> qt=15-(r>>5), else (r-256)>>5.
// S^T = mfma32(K, Q): lane holds 32 P-values for ONE q-row -> softmax fully
// in-register. P's native half-interleaved key order crow(j,hh)=pi(hh*8+j)
// IS the A-fragment under the pi-relabeled contraction (V pre-permuted), so
// the PV A-operand is a direct register pack: NO cross-lane ops at all.
__global__ __launch_bounds__(256, 2) void mla_attn(
    const __bf16* __restrict__ Qf, const __bf16* __restrict__ Kf,
    const __bf16* __restrict__ Vt, __bf16* __restrict__ ctx) {
  __shared__ __align__(16) __bf16 Ks[2][64 * 128];  // [key][dh], swz (row&15)
  __shared__ __align__(16) __bf16 Vs[2][128 * 64];  // [dh][key'], swz (row&7)

  const int r_ = (int)blockIdx.x;
  const int qt = (r_ < 256) ? (15 - (r_ >> 5)) : ((r_ - 256) >> 5);
  const int bh = r_ & 31;            // XCD class r%8 == bh%8: all 16 q-tiles
  const int h = bh >> 1, b = bh & 1; // of one (b,h) share an XCD L2
  const int tid = threadIdx.x, wid = tid >> 6, lane = tid & 63;
  const int l31 = lane & 31;
  const bool hh = (lane & 32) != 0;  // half index

  const __bf16* Kbh = Kf + (size_t)b * 2048 * 2048 + h * 128;
  const __bf16* Vbh = Vt + (size_t)h * 128 * 4096 + b * 2048;

  auto stage = [&](int k0, int buf) {
#pragma unroll
    for (int i = 0; i < 4; i++) {
      int e = i * 2048 + tid * 8;
      int krow = e >> 7;
      int kcol = (e & 127) ^ (8 * (krow & 15));
      async16(Kbh + (size_t)(k0 + krow) * 2048 + kcol,
              &Ks[buf][i * 2048 + wid * 512]);
    }
#pragma unroll
    for (int i = 0; i < 4; i++) {
      int e = i * 2048 + tid * 8;
      int vrow = e >> 6;
      int vcol = (e & 63) ^ (8 * (vrow & 7));
      async16(Vbh + (size_t)vrow * 4096 + k0 + vcol,
              &Vs[buf][i * 2048 + wid * 512]);
    }
  };

  const int q0 = qt * 128;
  const int nkv = 2 * qt + 2;         // 64-key tiles
  const int q = q0 + wid * 32 + l31;  // this lane's q-row

  // Q fragments (B-operand layout: col=q=lane&31, k-rows (lane>>5)*8+j)
  bf16x8 qb[8];
  const __bf16* qrow =
      Qf + (size_t)(b * 2048 + q) * 2048 + h * 128 + (hh ? 8 : 0);
#pragma unroll
  for (int ds = 0; ds < 8; ds++) qb[ds] = *(const bf16x8*)(qrow + ds * 16);

  f32x16 o[4] = {};
  float mrow = -1e30f, lsum = 0.f;

  int cur = 0;
  stage(0, 0);

  for (int kb = 0; kb < nkv; kb++) {
    const int k0 = kb * 64;
    __syncthreads();  // buf[cur] staged; buf[cur^1] free
    if (kb + 1 < nkv) stage(k0 + 64, cur ^ 1);

    // S^T = K Q^T : sacc[kt][r] = S[key = k0+kt*32+(r&3)+8*(r>>2)+4*hh][q]
    f32x16 sacc[2] = {};
    __builtin_amdgcn_s_setprio(1);
#pragma unroll
    for (int ds = 0; ds < 8; ds++) {
#pragma unroll
      for (int kt = 0; kt < 2; kt++) {
        int row = kt * 32 + l31;
        int col = (ds * 16 + (hh ? 8 : 0)) ^ (8 * (row & 15));
        bf16x8 kf = *(const bf16x8*)(&Ks[cur][row * 128 + col]);
        sacc[kt] = mfma32(kf, qb[ds], sacc[kt]);
      }
    }
    __builtin_amdgcn_s_setprio(0);

    // causal mask (last two tiles only) -- true (unpermuted) key indices
    if (kb >= 2 * qt) {
#pragma unroll
      for (int kt = 0; kt < 2; kt++)
#pragma unroll
        for (int r = 0; r < 16; r++) {
          int key = k0 + kt * 32 + (r & 3) + 8 * (r >> 2) + (hh ? 4 : 0);
          if (key > q) sacc[kt][r] = -1e30f;
        }
    }

    // in-register online softmax (s already in log2 units); pairwise max tree
    float t[16];
#pragma unroll
    for (int r = 0; r < 16; r++) t[r] = fmaxf(sacc[0][r], sacc[1][r]);
#pragma unroll
    for (int s = 8; s; s >>= 1)
#pragma unroll
      for (int r = 0; r < s; r++) t[r] = fmaxf(t[r], t[r + s]);
    float pm = fmaxf(t[0], __shfl_xor(t[0], 32));

    if (__any(pm > mrow + 8.f)) {  // deferred rescale (THR=8 log2)
      float mn = fmaxf(mrow, pm);
      float sf = __builtin_amdgcn_exp2f(mrow - mn);
      mrow = mn;
      lsum *= sf;
#pragma unroll
      for (int r = 0; r < 16; r++) {
        int ql = (r & 3) + 8 * (r >> 2) + (hh ? 4 : 0);
        float sr = __shfl(sf, ql);
#pragma unroll
        for (int dt = 0; dt < 4; dt++) o[dt][r] *= sr;
      }
    }
    float ps0 = 0.f, ps1 = 0.f, ps2 = 0.f, ps3 = 0.f;  // striped partial sums
#pragma unroll
    for (int kt = 0; kt < 2; kt++)
#pragma unroll
      for (int r = 0; r < 16; r += 4) {
        float a0 = __builtin_amdgcn_exp2f(sacc[kt][r + 0] - mrow);
        float a1 = __builtin_amdgcn_exp2f(sacc[kt][r + 1] - mrow);
        float a2 = __builtin_amdgcn_exp2f(sacc[kt][r + 2] - mrow);
        float a3 = __builtin_amdgcn_exp2f(sacc[kt][r + 3] - mrow);
        sacc[kt][r + 0] = a0; sacc[kt][r + 1] = a1;
        sacc[kt][r + 2] = a2; sacc[kt][r + 3] = a3;
        ps0 += a0; ps1 += a1; ps2 += a2; ps3 += a3;
      }
    float ps = (ps0 + ps1) + (ps2 + ps3);
    ps += __shfl_xor(ps, 32);
    lsum += ps;

    // O += P V : A-fragment = DIRECT pack of sacc (no cross-lane exchange;
    // V's key axis is pre-permuted by pi so A cols hh*8+j <-> crow(j,hh)).
    __builtin_amdgcn_s_setprio(1);
#pragma unroll
    for (int s = 0; s < 4; s++) {
      const int kt = s >> 1, r8 = (s & 1) * 8;
      u32x4 wv;
      wv.x = pk(sacc[kt][r8 + 0], sacc[kt][r8 + 1]);
      wv.y = pk(sacc[kt][r8 + 2], sacc[kt][r8 + 3]);
      wv.z = pk(sacc[kt][r8 + 4], sacc[kt][r8 + 5]);
      wv.w = pk(sacc[kt][r8 + 6], sacc[kt][r8 + 7]);
      bf16x8 pa = __builtin_bit_cast(bf16x8, wv);
#pragma unroll
      for (int dt = 0; dt < 4; dt++) {
        int vrow = dt * 32 + l31;
        int vcol = (s * 16 + (hh ? 8 : 0)) ^ (8 * (vrow & 7));
        bf16x8 vf = *(const bf16x8*)(&Vs[cur][vrow * 64 + vcol]);
        o[dt] = mfma32(pa, vf, o[dt]);
      }
    }
    __builtin_amdgcn_s_setprio(0);
    cur ^= 1;
  }

  // epilogue: normalize, gather per-row inv, write ctx
  float inv = 1.f / lsum;
#pragma unroll
  for (int r = 0; r < 16; r++) {
    int ql = (r & 3) + 8 * (r >> 2) + (hh ? 4 : 0);
    float ir = __shfl(inv, ql);
    size_t rowi = (size_t)(b * 2048 + q0 + wid * 32 + ql) * 2048 + h * 128;
#pragma unroll
    for (int dt = 0; dt < 4; dt++)
      ctx[rowi + dt * 32 + l31] = (__bf16)(o[dt][r] * ir);
  }
}

// ---------------- launch ----------------
extern "C" void kernel_launch(void* const* d_in, const int* in_sizes, int n_in,
                              void* d_out, int out_size, void* d_ws, size_t ws_size,
                              hipStream_t stream) {
  (void)in_sizes; (void)n_in; (void)out_size; (void)ws_size;
  const float* x    = (const float*)d_in[0];
  const float* wqd  = (const float*)d_in[1];
  const float* wkvd = (const float*)d_in[2];
  const float* wqup = (const float*)d_in[3];
  const float* wkup = (const float*)d_in[4];
  const float* wvup = (const float*)d_in[5];
  const float* wo   = (const float*)d_in[6];
  const float* bo   = (const float*)d_in[7];

  char* ws = (char*)d_ws;
  const size_t MB = 1024 * 1024;
  __bf16* x_bf     = (__bf16*)(ws + 0);        // 16MB; reused as ctx
  __bf16* q_full   = (__bf16*)(ws + 16 * MB);  // 16MB
  __bf16* k_full   = (__bf16*)(ws + 32 * MB);  // 16MB
  __bf16* vt       = (__bf16*)(ws + 48 * MB);  // 16MB (key axis pi-permuted)
  __bf16* qkv_lat  = (__bf16*)(ws + 64 * MB);  // 12MB [4096,1536]; reused wo_bf
  __bf16* wqkvd_bf = (__bf16*)(ws + 76 * MB);  // 6MB  [1536,2048] fused
  __bf16* wqup_bf  = (__bf16*)(ws + 82 * MB);  // 4MB
  __bf16* wkup_bf  = (__bf16*)(ws + 86 * MB);  // 2MB
  __bf16* wvup_bf  = (__bf16*)(ws + 88 * MB);  // 2MB -> total 90MB
  __bf16* ctx   = x_bf;      // x_bf dead after fused down-proj
  __bf16* wo_bf = qkv_lat;   // qkv_lat dead after V^T GEMM

  // conversions: x (8192 blocks) + all five projection weights (one launch)
  cvt_bf16<<<8192, 256, 0, stream>>>(x, x_bf);
  cvt_w<<<7168, 256, 0, stream>>>(wqd, wkvd, wqup, wkup, wvup, wqkvd_bf,
                                  wqup_bf, wkup_bf, wvup_bf);

  dim3 blk(256);
  // [Q_lat | C_kv] = x @ [Wq_down; Wkv_down]^T   (fused, N=1536)
  gemm_bt<0><<<dim3(32, 12), blk, 0, stream>>>(x_bf, wqkvd_bf, qkv_lat, nullptr,
                                               2048, 2048, 1536, 1536, 2048, 1.0f);
  // Q = Q_lat @ Wq_up^T, pre-scaled by L2E/sqrt(128) (softmax uses exp2)
  gemm_bt<0><<<dim3(32, 16), blk, 0, stream>>>(qkv_lat, wqup_bf, q_full, nullptr,
                                               1536, 1024, 2048, 2048, 1024,
                                               0.12752039360437355f);
  // K = C_kv @ Wk_up^T
  gemm_bt<0><<<dim3(32, 16), blk, 0, stream>>>(qkv_lat + 1024, wkup_bf, k_full,
                                               nullptr, 1536, 512, 2048, 2048,
                                               512, 1.0f);
  // V^T = Wv_up @ C_kv^T, key (token) axis stored pi-permuted (PERMN=1)
  gemm_bt<0, 1><<<dim3(16, 32), blk, 0, stream>>>(wvup_bf, qkv_lat + 1024, vt,
                                                  nullptr, 512, 1536, 4096, 4096,
                                                  512, 1.0f);
  cvt_bf16<<<4096, 256, 0, stream>>>(wo, wo_bf);  // qkv_lat free after V^T
  // ctx = causal_attention(Q, K, V)
  mla_attn<<<512, blk, 0, stream>>>(q_full, k_full, vt, ctx);
  // out = ctx @ Wo^T + bo  (fp32)
  gemm_bt<1><<<dim3(32, 16), blk, 0, stream>>>(ctx, wo_bf, (float*)d_out, bo,
                                               2048, 2048, 2048, 2048, 2048, 1.0f);
}